// Round 1
// baseline (434.766 us; speedup 1.0000x reference)
//
#include <hip/hip_runtime.h>

#define NUM_CELLS 8192
#define COLS 1024

// 4-byte-aligned float4 for the odd-offset W' output region (starts at elem 16385)
typedef float vf4 __attribute__((ext_vector_type(4)));
typedef vf4 uvf4 __attribute__((aligned(4)));

// Pass 1: new_active (d_out[0..8191]), anomaly (d_out[16384]), learn-gate flag (ws[0])
__global__ __launch_bounds__(1024) void prep_kernel(
    const float* __restrict__ act_cols, const float* __restrict__ pred,
    const float* __restrict__ prev, float* __restrict__ out,
    float* __restrict__ ws) {
  const int t = threadIdx.x;  // one thread per column, 1024 threads
  float p[8];
  float colsum = 0.f;
#pragma unroll
  for (int k = 0; k < 8; k++) { p[k] = pred[t * 8 + k]; colsum += p[k]; }
  const bool has_pred = colsum > 0.f;
  const bool active = act_cols[t] > 0.f;
#pragma unroll
  for (int k = 0; k < 8; k++)
    out[t * 8 + k] = active ? (has_pred ? p[k] : 1.f) : 0.f;

  float nA = active ? 1.f : 0.f;
  float nP = (active && has_pred) ? 1.f : 0.f;
  float ps = 0.f;
#pragma unroll
  for (int k = 0; k < 8; k++) ps += prev[t * 8 + k];

#pragma unroll
  for (int off = 32; off; off >>= 1) {
    nA += __shfl_down(nA, off);
    nP += __shfl_down(nP, off);
    ps += __shfl_down(ps, off);
  }
  __shared__ float sA[16], sP[16], sS[16];
  const int wid = t >> 6;
  if ((t & 63) == 0) { sA[wid] = nA; sP[wid] = nP; sS[wid] = ps; }
  __syncthreads();
  if (t == 0) {
    float a = 0.f, pp = 0.f, s = 0.f;
    for (int i = 0; i < 16; i++) { a += sA[i]; pp += sP[i]; s += sS[i]; }
    out[2 * NUM_CELLS] = 1.0f - pp / fmaxf(a, 1.0f);  // anomaly
    ws[0] = (s > 0.f) ? 1.f : 0.f;                    // learn gate
  }
}

// Pass 2: fused (connected @ new_active) row-reduction + permanence update.
// One block per row; 256 threads x 8 float4 = 8192 elements.
__global__ __launch_bounds__(256) void fused_kernel(
    const float* __restrict__ W, const float* __restrict__ prev,
    float* __restrict__ out, const float* __restrict__ ws) {
  const int row = blockIdx.x;
  const int t = threadIdx.x;
  const float coef = prev[row] * ws[0];  // 0 or 1, wave-uniform per block
  const float4* __restrict__ Wrow = (const float4*)(W + (size_t)row * NUM_CELLS);
  const float4* __restrict__ A = (const float4*)out;  // new_active lives at d_out[0..8191]
  uvf4* __restrict__ Wout = (uvf4*)(out + 2 * NUM_CELLS + 1 + (size_t)row * NUM_CELLS);

  float sum = 0.f;
  if (coef > 0.f) {
#pragma unroll
    for (int k = 0; k < 8; k++) {
      const int idx = k * 256 + t;
      const float4 w = Wrow[idx];
      const float4 a = A[idx];
      sum += ((w.x >= 0.5f) ? a.x : 0.f) + ((w.y >= 0.5f) ? a.y : 0.f) +
             ((w.z >= 0.5f) ? a.z : 0.f) + ((w.w >= 0.5f) ? a.w : 0.f);
      uvf4 u;
      u.x = fminf(fmaxf(w.x + ((a.x > 0.5f) ? 0.1f : -0.01f), 0.f), 1.f);
      u.y = fminf(fmaxf(w.y + ((a.y > 0.5f) ? 0.1f : -0.01f), 0.f), 1.f);
      u.z = fminf(fmaxf(w.z + ((a.z > 0.5f) ? 0.1f : -0.01f), 0.f), 1.f);
      u.w = fminf(fmaxf(w.w + ((a.w > 0.5f) ? 0.1f : -0.01f), 0.f), 1.f);
      Wout[idx] = u;
    }
  } else {
#pragma unroll
    for (int k = 0; k < 8; k++) {
      const int idx = k * 256 + t;
      const float4 w = Wrow[idx];
      const float4 a = A[idx];
      sum += ((w.x >= 0.5f) ? a.x : 0.f) + ((w.y >= 0.5f) ? a.y : 0.f) +
             ((w.z >= 0.5f) ? a.z : 0.f) + ((w.w >= 0.5f) ? a.w : 0.f);
      uvf4 u = {w.x, w.y, w.z, w.w};
      Wout[idx] = u;  // pass-through copy
    }
  }

  // block reduction: 4 waves
#pragma unroll
  for (int off = 32; off; off >>= 1) sum += __shfl_down(sum, off);
  __shared__ float s[4];
  if ((t & 63) == 0) s[t >> 6] = sum;
  __syncthreads();
  if (t == 0) {
    const float tot = s[0] + s[1] + s[2] + s[3];
    out[NUM_CELLS + row] = (tot >= 13.0f) ? 1.f : 0.f;  // new_predictive
  }
}

extern "C" void kernel_launch(void* const* d_in, const int* in_sizes, int n_in,
                              void* d_out, int out_size, void* d_ws, size_t ws_size,
                              hipStream_t stream) {
  const float* act_cols = (const float*)d_in[0];  // [1024]
  const float* W = (const float*)d_in[1];         // [8192*8192]
  const float* pred = (const float*)d_in[2];      // [8192]
  const float* prev = (const float*)d_in[3];      // [8192]
  float* out = (float*)d_out;
  float* ws = (float*)d_ws;

  prep_kernel<<<1, 1024, 0, stream>>>(act_cols, pred, prev, out, ws);
  fused_kernel<<<NUM_CELLS, 256, 0, stream>>>(W, prev, out, ws);
}